// Round 1
// baseline (4511.215 us; speedup 1.0000x reference)
//
#include <hip/hip_runtime.h>

typedef float f32x4v __attribute__((ext_vector_type(4)));
typedef __bf16 bf16x8 __attribute__((ext_vector_type(8)));

__device__ __forceinline__ ushort f2bf(float f) {
    unsigned u = __builtin_bit_cast(unsigned, f);
    return (ushort)((u + 0x7FFFu + ((u >> 16) & 1u)) >> 16);
}

// LDS offset in bf16 elements: rows of 32 elems (64B), 16B-slot XOR swizzle
__device__ __forceinline__ int lds_off(int row, int slot) {
    return row * 32 + (((slot ^ ((row >> 1) & 3)) & 3) << 3);
}

struct Ptr3 { const float* a; const float* b; const float* c; };

// ---------------------------------------------------------------------------
// GEMM: C[M,N] (+epilogue) = A[M,K](bf16) * B[K,N](f32, converted in staging)
// EPI: 0 = C=acc ; 1 = C+=acc ; 2 = Obf=bf16(relu(acc)^2) ; 3 = C+=sigmoid(G)*acc
// ---------------------------------------------------------------------------
template <int BM, int EPI>
__launch_bounds__(256, 2)
__global__ void gemm_k(const ushort* __restrict__ Abase, Ptr3 Bp,
                       float* __restrict__ Cbase, ushort* __restrict__ ObfBase,
                       const float* __restrict__ Gbase,
                       int M, int N, int K, int mtiles)
{
    constexpr int BN = 128, WM = BM / 2, WN = 64, MF = WM / 16, NF = 4, BK = 32;
    __shared__ ushort As[2][BM * 32];
    __shared__ ushort Bs[2][BN * 32];

    const int z = blockIdx.z;
    const ushort* A = Abase + (size_t)z * M * K;
    const float* B = (z == 0) ? Bp.a : ((z == 1) ? Bp.b : Bp.c);
    float* C = Cbase ? Cbase + (size_t)z * M * N : nullptr;
    ushort* Obf = ObfBase ? ObfBase + (size_t)z * M * N : nullptr;

    int bid = blockIdx.x;
    {   // XCD-aware swizzle (grids are multiples of 8)
        int nwg = gridDim.x;
        if ((nwg & 7) == 0) { int cpx = nwg >> 3; bid = (bid & 7) * cpx + (bid >> 3); }
    }
    const int mt = bid % mtiles, nt = bid / mtiles;
    const int m0 = mt * BM, n0 = nt * BN;
    const int tid = threadIdx.x;
    const int w = tid >> 6, l = tid & 63;
    const int wr = w >> 1, wc = w & 1, g = l >> 4, lr = l & 15;
    const bool ntail = (n0 + BN > N);

    constexpr int AS = (BM * 4) / 256;  // 16B A-slots per thread
    bf16x8 aR[AS];
    float4 bR[4];
    const int bn4 = (tid >> 3) * 4;   // 0..124 (col within tile)
    const int bk4 = (tid & 7) * 4;    // 0..28  (k within tile)

    auto ldA = [&](int k0) {
#pragma unroll
        for (int i = 0; i < AS; i++) {
            int s = tid + i * 256;
            int r = s >> 2, seg = s & 3;
            aR[i] = *(const bf16x8*)(A + (size_t)(m0 + r) * K + k0 + seg * 8);
        }
    };
    auto ldB = [&](int k0) {
        if (!ntail || (n0 + bn4 + 3 < N)) {
#pragma unroll
            for (int j = 0; j < 4; j++)
                bR[j] = *(const float4*)(B + (size_t)(k0 + bk4 + j) * N + n0 + bn4);
        } else {
#pragma unroll
            for (int j = 0; j < 4; j++) {
                float* p = &bR[j].x;
#pragma unroll
                for (int i = 0; i < 4; i++) {
                    int n = n0 + bn4 + i;
                    p[i] = (n < N) ? B[(size_t)(k0 + bk4 + j) * N + n] : 0.f;
                }
            }
        }
    };
    auto stA = [&](int buf) {
#pragma unroll
        for (int i = 0; i < AS; i++) {
            int s = tid + i * 256;
            int r = s >> 2, seg = s & 3;
            *(bf16x8*)(&As[buf][lds_off(r, seg)]) = aR[i];
        }
    };
    auto stB = [&](int buf) {
        int slot = bk4 >> 3, half = (bk4 >> 2) & 1;
#pragma unroll
        for (int i = 0; i < 4; i++) {
            int row = bn4 + i;
            uint lo = (uint)f2bf((&bR[0].x)[i]) | ((uint)f2bf((&bR[1].x)[i]) << 16);
            uint hi = (uint)f2bf((&bR[2].x)[i]) | ((uint)f2bf((&bR[3].x)[i]) << 16);
            uint2 val; val.x = lo; val.y = hi;
            *(uint2*)(&Bs[buf][lds_off(row, slot) + half * 4]) = val;
        }
    };

    f32x4v acc[MF][NF] = {};

    auto comp = [&](int buf) {
        bf16x8 af[MF], bfr[NF];
#pragma unroll
        for (int mi = 0; mi < MF; mi++)
            af[mi] = *(const bf16x8*)(&As[buf][lds_off(wr * WM + mi * 16 + lr, g)]);
#pragma unroll
        for (int ni = 0; ni < NF; ni++)
            bfr[ni] = *(const bf16x8*)(&Bs[buf][lds_off(wc * WN + ni * 16 + lr, g)]);
#pragma unroll
        for (int mi = 0; mi < MF; mi++)
#pragma unroll
            for (int ni = 0; ni < NF; ni++)
                acc[mi][ni] = __builtin_amdgcn_mfma_f32_16x16x32_bf16(
                    af[mi], bfr[ni], acc[mi][ni], 0, 0, 0);
    };

    const int NS = K / BK;
    ldA(0); ldB(0);
    stA(0); stB(0);
    for (int s = 0; s < NS; s++) {
        if (s + 1 < NS) { ldA((s + 1) * BK); ldB((s + 1) * BK); }
        __syncthreads();
        comp(s & 1);
        if (s + 1 < NS) { stA((s + 1) & 1); stB((s + 1) & 1); }
    }

    // epilogue: D col = lane&15, row = 4*(lane>>4)+q  (verified map)
#pragma unroll
    for (int mi = 0; mi < MF; mi++) {
        int row = m0 + wr * WM + mi * 16 + 4 * g;
#pragma unroll
        for (int ni = 0; ni < NF; ni++) {
            int col = n0 + wc * WN + ni * 16 + lr;
            if (ntail && col >= N) continue;
#pragma unroll
            for (int q = 0; q < 4; q++) {
                size_t idx = (size_t)(row + q) * N + col;
                float vv = acc[mi][ni][q];
                if constexpr (EPI == 0) {
                    C[idx] = vv;
                } else if constexpr (EPI == 1) {
                    C[idx] += vv;
                } else if constexpr (EPI == 2) {
                    float t = vv > 0.f ? vv : 0.f;
                    Obf[idx] = f2bf(t * t);
                } else {
                    float gt = 1.f / (1.f + __expf(-Gbase[idx]));
                    C[idx] += gt * vv;
                }
            }
        }
    }
}

// ---------------------------------------------------------------------------
// Block reduce of 4 floats over 256 threads (result identical on all threads)
// ---------------------------------------------------------------------------
__device__ __forceinline__ float4 blockReduce4(float4 v) {
#pragma unroll
    for (int off = 32; off; off >>= 1) {
        v.x += __shfl_down(v.x, off);
        v.y += __shfl_down(v.y, off);
        v.z += __shfl_down(v.z, off);
        v.w += __shfl_down(v.w, off);
    }
    __shared__ float4 red[4];
    int tid = threadIdx.x;
    if ((tid & 63) == 0) red[tid >> 6] = v;
    __syncthreads();
    float4 r = red[0];
    r.x += red[1].x + red[2].x + red[3].x;
    r.y += red[1].y + red[2].y + red[3].y;
    r.z += red[1].z + red[2].z + red[3].z;
    r.w += red[1].w + red[2].w + red[3].w;
    return r;
}

__global__ void embed_ln0(const int* __restrict__ tokens, const float* __restrict__ emb,
                          const float* __restrict__ g, const float* __restrict__ be,
                          float* __restrict__ x)
{
    int tau = blockIdx.x, tid = threadIdx.x;
    const float* e = emb + (size_t)tokens[tau] * 768;
    float a[3]; float s1 = 0, s2 = 0;
#pragma unroll
    for (int i = 0; i < 3; i++) {
        float av = e[tid + i * 256]; a[i] = av; s1 += av; s2 += av * av;
    }
    float4 r = blockReduce4(make_float4(s1, s2, 0.f, 0.f));
    const float inv = 1.f / 768.f;
    float m = r.x * inv, va = r.y * inv - m * m, rs = rsqrtf(va + 1e-5f);
#pragma unroll
    for (int i = 0; i < 3; i++) {
        int d = tid + i * 256;
        x[(size_t)tau * 768 + d] = (a[i] - m) * rs * g[d] + be[d];
    }
}

__global__ void ln_mix_tm(const float* __restrict__ x,
                          const float* __restrict__ g, const float* __restrict__ be,
                          const float* __restrict__ muk, const float* __restrict__ muv,
                          const float* __restrict__ mur,
                          ushort* __restrict__ xk, ushort* __restrict__ xv,
                          ushort* __restrict__ xr)
{
    int tau = blockIdx.x, tid = threadIdx.x;
    bool hasp = (tau & 511) != 0;
    const float* xp = x + (size_t)tau * 768;
    const float* pp = xp - 768;
    float a[3], b[3]; float s1 = 0, s2 = 0, s3 = 0, s4 = 0;
#pragma unroll
    for (int i = 0; i < 3; i++) {
        int d = tid + i * 256;
        float av = xp[d]; a[i] = av; s1 += av; s2 += av * av;
        float bv = hasp ? pp[d] : 0.f; b[i] = bv; s3 += bv; s4 += bv * bv;
    }
    float4 r = blockReduce4(make_float4(s1, s2, s3, s4));
    const float inv = 1.f / 768.f;
    float m1 = r.x * inv, va = r.y * inv - m1 * m1, rs1 = rsqrtf(va + 1e-5f);
    float m2 = r.z * inv, vb = r.w * inv - m2 * m2, rs2 = rsqrtf(vb + 1e-5f);
#pragma unroll
    for (int i = 0; i < 3; i++) {
        int d = tid + i * 256;
        float gg = g[d], bb = be[d];
        float xx = (a[i] - m1) * rs1 * gg + bb;
        float sx = hasp ? ((b[i] - m2) * rs2 * gg + bb) : 0.f;
        size_t o = (size_t)tau * 768 + d;
        float mk = muk[d]; xk[o] = f2bf(xx * mk + sx * (1.f - mk));
        float mv = muv[d]; xv[o] = f2bf(xx * mv + sx * (1.f - mv));
        float mr = mur[d]; xr[o] = f2bf(xx * mr + sx * (1.f - mr));
    }
}

__global__ void ln_mix_cm(const float* __restrict__ x,
                          const float* __restrict__ g, const float* __restrict__ be,
                          const float* __restrict__ muk, const float* __restrict__ mur,
                          ushort* __restrict__ xk, ushort* __restrict__ xr)
{
    int tau = blockIdx.x, tid = threadIdx.x;
    bool hasp = (tau & 511) != 0;
    const float* xp = x + (size_t)tau * 768;
    const float* pp = xp - 768;
    float a[3], b[3]; float s1 = 0, s2 = 0, s3 = 0, s4 = 0;
#pragma unroll
    for (int i = 0; i < 3; i++) {
        int d = tid + i * 256;
        float av = xp[d]; a[i] = av; s1 += av; s2 += av * av;
        float bv = hasp ? pp[d] : 0.f; b[i] = bv; s3 += bv; s4 += bv * bv;
    }
    float4 r = blockReduce4(make_float4(s1, s2, s3, s4));
    const float inv = 1.f / 768.f;
    float m1 = r.x * inv, va = r.y * inv - m1 * m1, rs1 = rsqrtf(va + 1e-5f);
    float m2 = r.z * inv, vb = r.w * inv - m2 * m2, rs2 = rsqrtf(vb + 1e-5f);
#pragma unroll
    for (int i = 0; i < 3; i++) {
        int d = tid + i * 256;
        float gg = g[d], bb = be[d];
        float xx = (a[i] - m1) * rs1 * gg + bb;
        float sx = hasp ? ((b[i] - m2) * rs2 * gg + bb) : 0.f;
        size_t o = (size_t)tau * 768 + d;
        float mk = muk[d]; xk[o] = f2bf(xx * mk + sx * (1.f - mk));
        float mr = mur[d]; xr[o] = f2bf(xx * mr + sx * (1.f - mr));
    }
}

__global__ void ln_final(const float* __restrict__ x,
                         const float* __restrict__ g, const float* __restrict__ be,
                         ushort* __restrict__ xf)
{
    int tau = blockIdx.x, tid = threadIdx.x;
    const float* xp = x + (size_t)tau * 768;
    float a[3]; float s1 = 0, s2 = 0;
#pragma unroll
    for (int i = 0; i < 3; i++) {
        float av = xp[tid + i * 256]; a[i] = av; s1 += av; s2 += av * av;
    }
    float4 r = blockReduce4(make_float4(s1, s2, 0.f, 0.f));
    const float inv = 1.f / 768.f;
    float m = r.x * inv, va = r.y * inv - m * m, rs = rsqrtf(va + 1e-5f);
#pragma unroll
    for (int i = 0; i < 3; i++) {
        int d = tid + i * 256;
        xf[(size_t)tau * 768 + d] = f2bf((a[i] - m) * rs * g[d] + be[d]);
    }
}

// ---------------------------------------------------------------------------
// WKV: serial scan per (b,d) channel, depth-8 register prefetch.
// Writes rwkv = bf16(sigmoid(r) * wkv)
// ---------------------------------------------------------------------------
__global__ void wkv_k(const float* __restrict__ kk, const float* __restrict__ vv,
                      const float* __restrict__ rr, const float* __restrict__ td,
                      const float* __restrict__ tf, ushort* __restrict__ out)
{
    int idx = blockIdx.x * 64 + threadIdx.x;  // < 1536
    int b = idx / 768, d = idx - b * 768;
    size_t base = (size_t)b * 512 * 768 + d;
    const float* kp = kk + base;
    const float* vp = vv + base;
    const float* rp = rr + base;
    ushort* op = out + base;
    float w = -__expf(td[d]);
    float u = tf[d];
    float p = -1e38f, aa = 0.f, bb = 0.f;
    const int CH = 8;
    float k8[CH], v8[CH], r8[CH], kn[CH], vn[CH], rn[CH];
#pragma unroll
    for (int j = 0; j < CH; j++) {
        k8[j] = kp[j * 768]; v8[j] = vp[j * 768]; r8[j] = rp[j * 768];
    }
    for (int c = 0; c < 512 / CH; c++) {
        if (c + 1 < 512 / CH) {
            size_t o = (size_t)(c + 1) * CH * 768;
#pragma unroll
            for (int j = 0; j < CH; j++) {
                kn[j] = kp[o + j * 768]; vn[j] = vp[o + j * 768]; rn[j] = rp[o + j * 768];
            }
        }
#pragma unroll
        for (int j = 0; j < CH; j++) {
            float kt = k8[j], vt = v8[j];
            float ww = u + kt;
            float q = fmaxf(p, ww);
            float e1 = __expf(p - q), e2 = __expf(ww - q);
            float o = (e1 * aa + e2 * vt) / (e1 * bb + e2);
            float sr = 1.f / (1.f + __expf(-r8[j]));
            op[(size_t)(c * CH + j) * 768] = f2bf(sr * o);
            float ww2 = p + w;
            float q2 = fmaxf(ww2, kt);
            float f1 = __expf(ww2 - q2), f2 = __expf(kt - q2);
            aa = f1 * aa + f2 * vt;
            bb = f1 * bb + f2;
            p = q2;
        }
#pragma unroll
        for (int j = 0; j < CH; j++) { k8[j] = kn[j]; v8[j] = vn[j]; r8[j] = rn[j]; }
    }
}

// ---------------------------------------------------------------------------
extern "C" void kernel_launch(void* const* d_in, const int* in_sizes, int n_in,
                              void* d_out, int out_size, void* d_ws, size_t ws_size,
                              hipStream_t stream)
{
    const int S = 512, V = 100300, D = 768, L = 12, H = 3072;
    const int T = 1024;  // B*S

    const int*   tokens     = (const int*)d_in[0];
    const float* emb        = (const float*)d_in[1];
    const float* ln0_g      = (const float*)d_in[2];
    const float* ln0_b      = (const float*)d_in[3];
    const float* ln1_g      = (const float*)d_in[4];
    const float* ln1_b      = (const float*)d_in[5];
    const float* ln2_g      = (const float*)d_in[6];
    const float* ln2_b      = (const float*)d_in[7];
    const float* time_decay = (const float*)d_in[8];
    const float* time_first = (const float*)d_in[9];
    const float* tm_mu_k    = (const float*)d_in[10];
    const float* tm_mu_v    = (const float*)d_in[11];
    const float* tm_mu_r    = (const float*)d_in[12];
    const float* tm_Wk      = (const float*)d_in[13];
    const float* tm_Wv      = (const float*)d_in[14];
    const float* tm_Wr      = (const float*)d_in[15];
    const float* tm_Wo      = (const float*)d_in[16];
    const float* cm_mu_k    = (const float*)d_in[17];
    const float* cm_mu_r    = (const float*)d_in[18];
    const float* cm_Wk      = (const float*)d_in[19];
    const float* cm_Wv      = (const float*)d_in[20];
    const float* cm_Wr      = (const float*)d_in[21];
    const float* lnf_g      = (const float*)d_in[22];
    const float* lnf_b      = (const float*)d_in[23];
    const float* head       = (const float*)d_in[24];

    char* wp = (char*)d_ws;
    auto alloc = [&](size_t bytes) -> char* {
        char* p = wp; wp += (bytes + 255) & ~(size_t)255; return p;
    };
    float*  x    = (float*)alloc((size_t)T * D * 4);
    ushort* xk   = (ushort*)alloc((size_t)3 * T * D * 2);  // xk, xv, xr contiguous
    float*  kvr  = (float*)alloc((size_t)3 * T * D * 4);   // k, v, r contiguous
    ushort* rwkv = (ushort*)alloc((size_t)T * D * 2);
    ushort* hbuf = (ushort*)alloc((size_t)T * H * 2);
    float*  rrb  = (float*)alloc((size_t)T * D * 4);
    ushort* xf   = (ushort*)alloc((size_t)T * D * 2);

    embed_ln0<<<T, 256, 0, stream>>>(tokens, emb, ln0_g, ln0_b, x);

    for (int l = 0; l < L; l++) {
        ln_mix_tm<<<T, 256, 0, stream>>>(x, ln1_g + l * D, ln1_b + l * D,
                                         tm_mu_k + l * D, tm_mu_v + l * D, tm_mu_r + l * D,
                                         xk, xk + (size_t)T * D, xk + (size_t)2 * T * D);

        Ptr3 bw{tm_Wk + (size_t)l * D * D, tm_Wv + (size_t)l * D * D, tm_Wr + (size_t)l * D * D};
        gemm_k<64, 0><<<dim3(96, 1, 3), 256, 0, stream>>>(xk, bw, kvr, nullptr, nullptr,
                                                          T, D, D, 16);

        wkv_k<<<24, 64, 0, stream>>>(kvr, kvr + (size_t)T * D, kvr + (size_t)2 * T * D,
                                     time_decay + l * D, time_first + l * D, rwkv);

        Ptr3 bo{tm_Wo + (size_t)l * D * D, nullptr, nullptr};
        gemm_k<64, 1><<<dim3(96, 1, 1), 256, 0, stream>>>(rwkv, bo, x, nullptr, nullptr,
                                                          T, D, D, 16);

        ln_mix_cm<<<T, 256, 0, stream>>>(x, ln2_g + l * D, ln2_b + l * D,
                                         cm_mu_k + l * D, cm_mu_r + l * D,
                                         xk, xk + (size_t)T * D);

        Ptr3 bk{cm_Wk + (size_t)l * D * H, nullptr, nullptr};
        gemm_k<64, 2><<<dim3(16 * (H / 128), 1, 1), 256, 0, stream>>>(xk, bk, nullptr, hbuf,
                                                                      nullptr, T, H, D, 16);

        Ptr3 br{cm_Wr + (size_t)l * D * D, nullptr, nullptr};
        gemm_k<64, 0><<<dim3(96, 1, 1), 256, 0, stream>>>(xk + (size_t)T * D, br, rrb, nullptr,
                                                          nullptr, T, D, D, 16);

        Ptr3 bv{cm_Wv + (size_t)l * H * D, nullptr, nullptr};
        gemm_k<64, 3><<<dim3(96, 1, 1), 256, 0, stream>>>(hbuf, bv, x, nullptr, rrb,
                                                          T, D, H, 16);
    }

    ln_final<<<T, 256, 0, stream>>>(x, lnf_g, lnf_b, xf);

    Ptr3 bh{head, nullptr, nullptr};
    gemm_k<128, 0><<<dim3(8 * 784, 1, 1), 256, 0, stream>>>(xf, bh, (float*)d_out, nullptr,
                                                            nullptr, T, V, D, 8);
}

// Round 2
// 2875.622 us; speedup vs baseline: 1.5688x; 1.5688x over previous
//
#include <hip/hip_runtime.h>

typedef float f32x4v __attribute__((ext_vector_type(4)));
typedef __bf16 bf16x8 __attribute__((ext_vector_type(8)));

__device__ __forceinline__ ushort f2bf(float f) {
    unsigned u = __builtin_bit_cast(unsigned, f);
    return (ushort)((u + 0x7FFFu + ((u >> 16) & 1u)) >> 16);
}

__device__ __forceinline__ void gload16(const void* g, void* l) {
    __builtin_amdgcn_global_load_lds(
        (const __attribute__((address_space(1))) void*)g,
        (__attribute__((address_space(3))) void*)l, 16, 0, 0);
}

// ---------------------------------------------------------------------------
// prep_w: W f32 [K][N] -> Wt bf16 [Npad][K]  (batched over blockIdx.z)
// rows n in [N,Npad) are zero-filled.
// ---------------------------------------------------------------------------
__global__ __launch_bounds__(256)
void prep_w(const float* __restrict__ Win, ushort* __restrict__ Wout,
            int K, int N, size_t sIn, size_t sOut)
{
    __shared__ float t[64][65];
    const float* W = Win + sIn * blockIdx.z;
    ushort* O = Wout + sOut * blockIdx.z;
    int n0 = blockIdx.x * 64, k0 = blockIdx.y * 64;
    int tid = threadIdx.x;
    int c = tid & 63, r4 = tid >> 6;
#pragma unroll
    for (int i = 0; i < 16; i++) {
        int rr = i * 4 + r4;
        int n = n0 + c;
        t[rr][c] = (n < N) ? W[(size_t)(k0 + rr) * N + n] : 0.f;
    }
    __syncthreads();
#pragma unroll
    for (int i = 0; i < 16; i++) {
        int nr = i * 4 + r4;
        O[(size_t)(n0 + nr) * K + k0 + c] = f2bf(t[c][nr]);
    }
}

// ---------------------------------------------------------------------------
// gemm2: C[M,N](+epi) = A[M,K](bf16 row-major) * Bt[N,K](bf16 row-major)
// m97 structure: BK=64, global_load_lds (16B), double-buffered LDS,
// XOR-swizzled via pre-swizzled global source + swizzled ds_read.
// EPI: 0 C=acc ; 1 C+=acc ; 2 Obf=bf16(relu(acc)^2) ; 3 C+=sigmoid(G)*acc
// ---------------------------------------------------------------------------
template <int BM, int BN, int EPI>
__global__ __launch_bounds__(256)
void gemm2(const ushort* __restrict__ Abase,
           const ushort* __restrict__ B0, const ushort* __restrict__ B1,
           const ushort* __restrict__ B2,
           float* __restrict__ Cbase, ushort* __restrict__ ObfBase,
           const float* __restrict__ Gbase,
           int M, int N, int K, int mtiles)
{
    constexpr int WM = BM / 2, WN = BN / 2, MF = WM / 16, NF = WN / 16, BK = 64;
    __shared__ ushort As[2][BM * 64];
    __shared__ ushort Bs[2][BN * 64];

    const int z = blockIdx.z;
    const ushort* A = Abase + (size_t)z * M * K;
    const ushort* B = (z == 0) ? B0 : ((z == 1) ? B1 : B2);
    float* C = Cbase ? Cbase + (size_t)z * M * N : nullptr;
    ushort* Obf = ObfBase ? ObfBase + (size_t)z * M * N : nullptr;

    int bid = blockIdx.x;
    {   // XCD-aware swizzle (all grids are multiples of 8)
        int nwg = gridDim.x;
        int cpx = nwg >> 3;
        bid = (bid & 7) * cpx + (bid >> 3);
    }
    const int mt = bid % mtiles, nt = bid / mtiles;
    const int m0 = mt * BM, n0 = nt * BN;
    const int tid = threadIdx.x;
    const int w = tid >> 6, l = tid & 63;
    const int wr = w >> 1, wc = w & 1, g = l >> 4, lr = l & 15;
    const bool ntail = (n0 + BN > N);

    const int lrow = l >> 3;                       // 0..7
    const int lcol = ((l & 7) ^ lrow) * 8;         // pre-swizzled source slot

    auto stage = [&](int buf, int k0) {
#pragma unroll
        for (int i = 0; i < BM / 32; i++) {
            int rb = (i * 4 + w) * 8;
            gload16(A + (size_t)(m0 + rb + lrow) * K + k0 + lcol, &As[buf][rb * 64]);
        }
#pragma unroll
        for (int i = 0; i < BN / 32; i++) {
            int rb = (i * 4 + w) * 8;
            gload16(B + (size_t)(n0 + rb + lrow) * K + k0 + lcol, &Bs[buf][rb * 64]);
        }
    };

    f32x4v acc[MF][NF] = {};

    auto comp = [&](int buf) {
#pragma unroll
        for (int kk = 0; kk < 2; kk++) {
            bf16x8 af[MF], bfr[NF];
            const int sl = ((kk * 4 + g) ^ (lr & 7)) * 8;   // swizzled read slot
#pragma unroll
            for (int mi = 0; mi < MF; mi++)
                af[mi] = *(const bf16x8*)(&As[buf][(wr * WM + mi * 16 + lr) * 64 + sl]);
#pragma unroll
            for (int ni = 0; ni < NF; ni++)
                bfr[ni] = *(const bf16x8*)(&Bs[buf][(wc * WN + ni * 16 + lr) * 64 + sl]);
#pragma unroll
            for (int mi = 0; mi < MF; mi++)
#pragma unroll
                for (int ni = 0; ni < NF; ni++)
                    acc[mi][ni] = __builtin_amdgcn_mfma_f32_16x16x32_bf16(
                        af[mi], bfr[ni], acc[mi][ni], 0, 0, 0);
        }
    };

    const int NS = K / BK;
    stage(0, 0);
    __syncthreads();
    for (int s = 0; s < NS; s++) {
        if (s + 1 < NS) stage((s + 1) & 1, (s + 1) * BK);
        comp(s & 1);
        __syncthreads();
    }

    // D map: col = lane&15, row = 4*(lane>>4)+q  (verified)
#pragma unroll
    for (int mi = 0; mi < MF; mi++) {
        int row = m0 + wr * WM + mi * 16 + 4 * g;
#pragma unroll
        for (int ni = 0; ni < NF; ni++) {
            int col = n0 + wc * WN + ni * 16 + lr;
            if (ntail && col >= N) continue;
#pragma unroll
            for (int q = 0; q < 4; q++) {
                size_t idx = (size_t)(row + q) * N + col;
                float vv = acc[mi][ni][q];
                if constexpr (EPI == 0) {
                    C[idx] = vv;
                } else if constexpr (EPI == 1) {
                    C[idx] += vv;
                } else if constexpr (EPI == 2) {
                    float t = vv > 0.f ? vv : 0.f;
                    Obf[idx] = f2bf(t * t);
                } else {
                    float gt = 1.f / (1.f + __expf(-Gbase[idx]));
                    C[idx] += gt * vv;
                }
            }
        }
    }
}

// ---------------------------------------------------------------------------
__device__ __forceinline__ float4 blockReduce4(float4 v) {
#pragma unroll
    for (int off = 32; off; off >>= 1) {
        v.x += __shfl_down(v.x, off);
        v.y += __shfl_down(v.y, off);
        v.z += __shfl_down(v.z, off);
        v.w += __shfl_down(v.w, off);
    }
    __shared__ float4 red[4];
    int tid = threadIdx.x;
    if ((tid & 63) == 0) red[tid >> 6] = v;
    __syncthreads();
    float4 r = red[0];
    r.x += red[1].x + red[2].x + red[3].x;
    r.y += red[1].y + red[2].y + red[3].y;
    r.z += red[1].z + red[2].z + red[3].z;
    r.w += red[1].w + red[2].w + red[3].w;
    return r;
}

__global__ void embed_ln0(const int* __restrict__ tokens, const float* __restrict__ emb,
                          const float* __restrict__ g, const float* __restrict__ be,
                          float* __restrict__ x)
{
    int tau = blockIdx.x, tid = threadIdx.x;
    const float* e = emb + (size_t)tokens[tau] * 768;
    float a[3]; float s1 = 0, s2 = 0;
#pragma unroll
    for (int i = 0; i < 3; i++) {
        float av = e[tid + i * 256]; a[i] = av; s1 += av; s2 += av * av;
    }
    float4 r = blockReduce4(make_float4(s1, s2, 0.f, 0.f));
    const float inv = 1.f / 768.f;
    float m = r.x * inv, va = r.y * inv - m * m, rs = rsqrtf(va + 1e-5f);
#pragma unroll
    for (int i = 0; i < 3; i++) {
        int d = tid + i * 256;
        x[(size_t)tau * 768 + d] = (a[i] - m) * rs * g[d] + be[d];
    }
}

__global__ void ln_mix_tm(const float* __restrict__ x,
                          const float* __restrict__ g, const float* __restrict__ be,
                          const float* __restrict__ muk, const float* __restrict__ muv,
                          const float* __restrict__ mur,
                          ushort* __restrict__ xk, ushort* __restrict__ xv,
                          ushort* __restrict__ xr)
{
    int tau = blockIdx.x, tid = threadIdx.x;
    bool hasp = (tau & 511) != 0;
    const float* xp = x + (size_t)tau * 768;
    const float* pp = xp - 768;
    float a[3], b[3]; float s1 = 0, s2 = 0, s3 = 0, s4 = 0;
#pragma unroll
    for (int i = 0; i < 3; i++) {
        int d = tid + i * 256;
        float av = xp[d]; a[i] = av; s1 += av; s2 += av * av;
        float bv = hasp ? pp[d] : 0.f; b[i] = bv; s3 += bv; s4 += bv * bv;
    }
    float4 r = blockReduce4(make_float4(s1, s2, s3, s4));
    const float inv = 1.f / 768.f;
    float m1 = r.x * inv, va = r.y * inv - m1 * m1, rs1 = rsqrtf(va + 1e-5f);
    float m2 = r.z * inv, vb = r.w * inv - m2 * m2, rs2 = rsqrtf(vb + 1e-5f);
#pragma unroll
    for (int i = 0; i < 3; i++) {
        int d = tid + i * 256;
        float gg = g[d], bb = be[d];
        float xx = (a[i] - m1) * rs1 * gg + bb;
        float sx = hasp ? ((b[i] - m2) * rs2 * gg + bb) : 0.f;
        size_t o = (size_t)tau * 768 + d;
        float mk = muk[d]; xk[o] = f2bf(xx * mk + sx * (1.f - mk));
        float mv = muv[d]; xv[o] = f2bf(xx * mv + sx * (1.f - mv));
        float mr = mur[d]; xr[o] = f2bf(xx * mr + sx * (1.f - mr));
    }
}

__global__ void ln_mix_cm(const float* __restrict__ x,
                          const float* __restrict__ g, const float* __restrict__ be,
                          const float* __restrict__ muk, const float* __restrict__ mur,
                          ushort* __restrict__ xk, ushort* __restrict__ xr)
{
    int tau = blockIdx.x, tid = threadIdx.x;
    bool hasp = (tau & 511) != 0;
    const float* xp = x + (size_t)tau * 768;
    const float* pp = xp - 768;
    float a[3], b[3]; float s1 = 0, s2 = 0, s3 = 0, s4 = 0;
#pragma unroll
    for (int i = 0; i < 3; i++) {
        int d = tid + i * 256;
        float av = xp[d]; a[i] = av; s1 += av; s2 += av * av;
        float bv = hasp ? pp[d] : 0.f; b[i] = bv; s3 += bv; s4 += bv * bv;
    }
    float4 r = blockReduce4(make_float4(s1, s2, s3, s4));
    const float inv = 1.f / 768.f;
    float m1 = r.x * inv, va = r.y * inv - m1 * m1, rs1 = rsqrtf(va + 1e-5f);
    float m2 = r.z * inv, vb = r.w * inv - m2 * m2, rs2 = rsqrtf(vb + 1e-5f);
#pragma unroll
    for (int i = 0; i < 3; i++) {
        int d = tid + i * 256;
        float gg = g[d], bb = be[d];
        float xx = (a[i] - m1) * rs1 * gg + bb;
        float sx = hasp ? ((b[i] - m2) * rs2 * gg + bb) : 0.f;
        size_t o = (size_t)tau * 768 + d;
        float mk = muk[d]; xk[o] = f2bf(xx * mk + sx * (1.f - mk));
        float mr = mur[d]; xr[o] = f2bf(xx * mr + sx * (1.f - mr));
    }
}

__global__ void ln_final(const float* __restrict__ x,
                         const float* __restrict__ g, const float* __restrict__ be,
                         ushort* __restrict__ xf)
{
    int tau = blockIdx.x, tid = threadIdx.x;
    const float* xp = x + (size_t)tau * 768;
    float a[3]; float s1 = 0, s2 = 0;
#pragma unroll
    for (int i = 0; i < 3; i++) {
        float av = xp[tid + i * 256]; a[i] = av; s1 += av; s2 += av * av;
    }
    float4 r = blockReduce4(make_float4(s1, s2, 0.f, 0.f));
    const float inv = 1.f / 768.f;
    float m = r.x * inv, va = r.y * inv - m * m, rs = rsqrtf(va + 1e-5f);
#pragma unroll
    for (int i = 0; i < 3; i++) {
        int d = tid + i * 256;
        xf[(size_t)tau * 768 + d] = f2bf((a[i] - m) * rs * g[d] + be[d]);
    }
}

// ---------------------------------------------------------------------------
// WKV: serial scan per (b,d) channel, depth-8 register prefetch.
// ---------------------------------------------------------------------------
__global__ void wkv_k(const float* __restrict__ kk, const float* __restrict__ vv,
                      const float* __restrict__ rr, const float* __restrict__ td,
                      const float* __restrict__ tf, ushort* __restrict__ out)
{
    int idx = blockIdx.x * 64 + threadIdx.x;
    int b = idx / 768, d = idx - b * 768;
    size_t base = (size_t)b * 512 * 768 + d;
    const float* kp = kk + base;
    const float* vp = vv + base;
    const float* rp = rr + base;
    ushort* op = out + base;
    float w = -__expf(td[d]);
    float u = tf[d];
    float p = -1e38f, aa = 0.f, bb = 0.f;
    const int CH = 8;
    float k8[CH], v8[CH], r8[CH], kn[CH], vn[CH], rn[CH];
#pragma unroll
    for (int j = 0; j < CH; j++) {
        k8[j] = kp[j * 768]; v8[j] = vp[j * 768]; r8[j] = rp[j * 768];
    }
    for (int c = 0; c < 512 / CH; c++) {
        if (c + 1 < 512 / CH) {
            size_t o = (size_t)(c + 1) * CH * 768;
#pragma unroll
            for (int j = 0; j < CH; j++) {
                kn[j] = kp[o + j * 768]; vn[j] = vp[o + j * 768]; rn[j] = rp[o + j * 768];
            }
        }
#pragma unroll
        for (int j = 0; j < CH; j++) {
            float kt = k8[j], vt = v8[j];
            float ww = u + kt;
            float q = fmaxf(p, ww);
            float e1 = __expf(p - q), e2 = __expf(ww - q);
            float o = (e1 * aa + e2 * vt) / (e1 * bb + e2);
            float sr = 1.f / (1.f + __expf(-r8[j]));
            op[(size_t)(c * CH + j) * 768] = f2bf(sr * o);
            float ww2 = p + w;
            float q2 = fmaxf(ww2, kt);
            float f1 = __expf(ww2 - q2), f2 = __expf(kt - q2);
            aa = f1 * aa + f2 * vt;
            bb = f1 * bb + f2;
            p = q2;
        }
#pragma unroll
        for (int j = 0; j < CH; j++) { k8[j] = kn[j]; v8[j] = vn[j]; r8[j] = rn[j]; }
    }
}

// ---------------------------------------------------------------------------
extern "C" void kernel_launch(void* const* d_in, const int* in_sizes, int n_in,
                              void* d_out, int out_size, void* d_ws, size_t ws_size,
                              hipStream_t stream)
{
    const int V = 100300, D = 768, L = 12, H = 3072;
    const int T = 1024;           // B*S
    const int Vp = 100352;        // V padded to 128

    const int*   tokens     = (const int*)d_in[0];
    const float* emb        = (const float*)d_in[1];
    const float* ln0_g      = (const float*)d_in[2];
    const float* ln0_b      = (const float*)d_in[3];
    const float* ln1_g      = (const float*)d_in[4];
    const float* ln1_b      = (const float*)d_in[5];
    const float* ln2_g      = (const float*)d_in[6];
    const float* ln2_b      = (const float*)d_in[7];
    const float* time_decay = (const float*)d_in[8];
    const float* time_first = (const float*)d_in[9];
    const float* tm_mu_k    = (const float*)d_in[10];
    const float* tm_mu_v    = (const float*)d_in[11];
    const float* tm_mu_r    = (const float*)d_in[12];
    const float* tm_Wk      = (const float*)d_in[13];
    const float* tm_Wv      = (const float*)d_in[14];
    const float* tm_Wr      = (const float*)d_in[15];
    const float* tm_Wo      = (const float*)d_in[16];
    const float* cm_mu_k    = (const float*)d_in[17];
    const float* cm_mu_r    = (const float*)d_in[18];
    const float* cm_Wk      = (const float*)d_in[19];
    const float* cm_Wv      = (const float*)d_in[20];
    const float* cm_Wr      = (const float*)d_in[21];
    const float* lnf_g      = (const float*)d_in[22];
    const float* lnf_b      = (const float*)d_in[23];
    const float* head       = (const float*)d_in[24];

    char* wp = (char*)d_ws;
    auto alloc = [&](size_t bytes) -> char* {
        char* p = wp; wp += (bytes + 255) & ~(size_t)255; return p;
    };
    const size_t eDD = (size_t)L * D * D;      // 12*768*768
    const size_t eDH = (size_t)L * D * H;
    ushort* wkT = (ushort*)alloc(eDD * 2);
    ushort* wvT = (ushort*)alloc(eDD * 2);
    ushort* wrT = (ushort*)alloc(eDD * 2);
    ushort* woT = (ushort*)alloc(eDD * 2);
    ushort* ckT = (ushort*)alloc(eDH * 2);     // [L][H][D]
    ushort* cvT = (ushort*)alloc(eDH * 2);     // [L][D][H]
    ushort* crT = (ushort*)alloc(eDD * 2);
    ushort* hdT = (ushort*)alloc((size_t)Vp * D * 2);

    float*  x    = (float*)alloc((size_t)T * D * 4);
    ushort* xk   = (ushort*)alloc((size_t)3 * T * D * 2);  // xk, xv, xr
    float*  kvr  = (float*)alloc((size_t)3 * T * D * 4);   // k, v, r
    ushort* rwkv = (ushort*)alloc((size_t)T * D * 2);
    ushort* hbuf = (ushort*)alloc((size_t)T * H * 2);
    float*  rrb  = (float*)alloc((size_t)T * D * 4);
    ushort* xf   = (ushort*)alloc((size_t)T * D * 2);

    // ---- weight prep (transpose + bf16) ----
    prep_w<<<dim3(D / 64, D / 64, L), 256, 0, stream>>>(tm_Wk, wkT, D, D, (size_t)D * D, (size_t)D * D);
    prep_w<<<dim3(D / 64, D / 64, L), 256, 0, stream>>>(tm_Wv, wvT, D, D, (size_t)D * D, (size_t)D * D);
    prep_w<<<dim3(D / 64, D / 64, L), 256, 0, stream>>>(tm_Wr, wrT, D, D, (size_t)D * D, (size_t)D * D);
    prep_w<<<dim3(D / 64, D / 64, L), 256, 0, stream>>>(tm_Wo, woT, D, D, (size_t)D * D, (size_t)D * D);
    prep_w<<<dim3(H / 64, D / 64, L), 256, 0, stream>>>(cm_Wk, ckT, D, H, (size_t)D * H, (size_t)D * H);
    prep_w<<<dim3(D / 64, H / 64, L), 256, 0, stream>>>(cm_Wv, cvT, H, D, (size_t)D * H, (size_t)D * H);
    prep_w<<<dim3(D / 64, D / 64, L), 256, 0, stream>>>(cm_Wr, crT, D, D, (size_t)D * D, (size_t)D * D);
    prep_w<<<dim3(Vp / 64, D / 64, 1), 256, 0, stream>>>(head, hdT, D, V, 0, 0);

    embed_ln0<<<T, 256, 0, stream>>>(tokens, emb, ln0_g, ln0_b, x);

    for (int l = 0; l < L; l++) {
        ln_mix_tm<<<T, 256, 0, stream>>>(x, ln1_g + l * D, ln1_b + l * D,
                                         tm_mu_k + l * D, tm_mu_v + l * D, tm_mu_r + l * D,
                                         xk, xk + (size_t)T * D, xk + (size_t)2 * T * D);

        gemm2<64, 64, 0><<<dim3(192, 1, 3), 256, 0, stream>>>(
            xk, wkT + l * (size_t)D * D, wvT + l * (size_t)D * D, wrT + l * (size_t)D * D,
            kvr, nullptr, nullptr, T, D, D, 16);

        wkv_k<<<24, 64, 0, stream>>>(kvr, kvr + (size_t)T * D, kvr + (size_t)2 * T * D,
                                     time_decay + l * D, time_first + l * D, rwkv);

        gemm2<64, 64, 1><<<dim3(192, 1, 1), 256, 0, stream>>>(
            rwkv, woT + l * (size_t)D * D, nullptr, nullptr,
            x, nullptr, nullptr, T, D, D, 16);

        ln_mix_cm<<<T, 256, 0, stream>>>(x, ln2_g + l * D, ln2_b + l * D,
                                         cm_mu_k + l * D, cm_mu_r + l * D,
                                         xk, xk + (size_t)T * D);

        gemm2<64, 128, 2><<<dim3(384, 1, 1), 256, 0, stream>>>(
            xk, ckT + l * (size_t)D * H, nullptr, nullptr,
            nullptr, hbuf, nullptr, T, H, D, 16);

        gemm2<64, 64, 0><<<dim3(192, 1, 1), 256, 0, stream>>>(
            xk + (size_t)T * D, crT + l * (size_t)D * D, nullptr, nullptr,
            rrb, nullptr, nullptr, T, D, D, 16);

        gemm2<64, 64, 3><<<dim3(192, 1, 1), 256, 0, stream>>>(
            hbuf, cvT + l * (size_t)D * H, nullptr, nullptr,
            x, nullptr, rrb, T, D, H, 16);
    }

    ln_final<<<T, 256, 0, stream>>>(x, lnf_g, lnf_b, xf);

    gemm2<128, 128, 0><<<dim3(8 * (Vp / 128), 1, 1), 256, 0, stream>>>(
        xf, hdT, nullptr, nullptr,
        (float*)d_out, nullptr, nullptr, T, V, D, 8);
}